// Round 6
// baseline (742.617 us; speedup 1.0000x reference)
//
#include <hip/hip_runtime.h>
#include <math.h>

#define NN 100000
#define NE 1600000
#define NG 1000
#define BN_EPS 1e-5f
#define AGG_BLOCKS 2048
#define NWAVES (AGG_BLOCKS * 4)
#define CAP 512      // per-wave LDS index cache (ints); balanced waves ~195+degmax edges
#define RNG 500      // nodes per bucket (200*500 == 100000)
#define NBUK 200
#define BB 512       // binning blocks
#define BCAP 12288   // per-bucket LDS edge capacity

typedef unsigned short ushort_t;
typedef unsigned int uint_t;

__device__ inline float bf2f(ushort_t u) {
    return __uint_as_float(((uint_t)u) << 16);
}
__device__ inline ushort_t f2bf(float f) {
    uint_t u = __float_as_uint(f);
    u += 0x7FFFu + ((u >> 16) & 1u);   // RNE
    return (ushort_t)(u >> 16);
}

// ---------------- init ----------------

__global__ __launch_bounds__(256) void k_init(float* pooled, float* stats, int* bcnt) {
    int i = blockIdx.x * blockDim.x + threadIdx.x;
    int stride = gridDim.x * blockDim.x;
    for (int j = i; j < 5 * NG * 64; j += stride) pooled[j] = 0.f;
    for (int j = i; j < 1024; j += stride) stats[j] = 0.f;
    for (int j = i; j < NBUK; j += stride) bcnt[j] = 0;
}

__global__ __launch_bounds__(256) void k_f2bf(const float4* __restrict__ x, uint2* __restrict__ o) {
    int i = blockIdx.x * blockDim.x + threadIdx.x;
    int stride = gridDim.x * blockDim.x;
    for (int j = i; j < NN * 16; j += stride) {
        float4 v = x[j];
        uint2 r;
        r.x = (uint_t)f2bf(v.x) | ((uint_t)f2bf(v.y) << 16);
        r.y = (uint_t)f2bf(v.z) | ((uint_t)f2bf(v.w) << 16);
        o[j] = r;
    }
}

// ---------------- CSR build: block-local counting sort ----------------

__global__ __launch_bounds__(256) void k_cnt(const int* __restrict__ dst,
                                             int* __restrict__ cmat, int* __restrict__ bcnt) {
    __shared__ int l[NBUK];
    int b = blockIdx.x;
    for (int t = threadIdx.x; t < NBUK; t += 256) l[t] = 0;
    __syncthreads();
    int per = (NE + BB - 1) / BB;
    int s = b * per, e = min(NE, s + per);
    for (int i = s + threadIdx.x; i < e; i += 256) atomicAdd(&l[dst[i] / RNG], 1);
    __syncthreads();
    for (int t = threadIdx.x; t < NBUK; t += 256) {
        cmat[b * NBUK + t] = l[t];
        if (l[t]) atomicAdd(&bcnt[t], l[t]);
    }
}

__global__ __launch_bounds__(256) void k_bucket_scan(const int* __restrict__ bcnt,
                                                     int* __restrict__ boff) {
    __shared__ int s[256];
    int t = threadIdx.x;
    int v = (t < NBUK) ? bcnt[t] : 0;
    s[t] = v;
    __syncthreads();
    for (int o = 1; o < 256; o <<= 1) {
        int x = (t >= o) ? s[t - o] : 0;
        __syncthreads();
        s[t] += x;
        __syncthreads();
    }
    if (t < NBUK) boff[t] = s[t] - v;
    if (t == 0) boff[NBUK] = NE;
}

__global__ __launch_bounds__(256) void k_boffscan(const int* __restrict__ cmat,
                                                  const int* __restrict__ boff,
                                                  int* __restrict__ wmat) {
    __shared__ int s[256];
    int k = blockIdx.x;
    int t = threadIdx.x;
    int c0 = cmat[(2 * t) * NBUK + k];
    int c1 = cmat[(2 * t + 1) * NBUK + k];
    int sum = c0 + c1;
    s[t] = sum;
    __syncthreads();
    for (int o = 1; o < 256; o <<= 1) {
        int x = (t >= o) ? s[t - o] : 0;
        __syncthreads();
        s[t] += x;
        __syncthreads();
    }
    int excl = s[t] - sum + boff[k];
    wmat[(2 * t) * NBUK + k] = excl;
    wmat[(2 * t + 1) * NBUK + k] = excl + c0;
}

__global__ __launch_bounds__(256) void k_bin2(const int* __restrict__ src, const int* __restrict__ dst,
                                              const int* __restrict__ wmat, uint_t* __restrict__ binned) {
    __shared__ int l[NBUK];
    int b = blockIdx.x;
    for (int t = threadIdx.x; t < NBUK; t += 256) l[t] = 0;
    __syncthreads();
    int per = (NE + BB - 1) / BB;
    int s = b * per, e = min(NE, s + per);
    for (int i = s + threadIdx.x; i < e; i += 256) {
        int d = dst[i];
        int k = d / RNG;
        int ldst = d - k * RNG;
        int r = atomicAdd(&l[k], 1);
        binned[wmat[b * NBUK + k] + r] = ((uint_t)ldst << 17) | (uint_t)src[i];
    }
}

__global__ __launch_bounds__(256) void k_bucket_finish(
    const uint_t* __restrict__ binned, const int* __restrict__ boff,
    int* __restrict__ off, int* __restrict__ csr)
{
    __shared__ uint_t ebuf[BCAP];
    __shared__ int cnt[512];
    __shared__ int a[256];
    __shared__ int wpos[RNG];
    int k = blockIdx.x;
    int t = threadIdx.x;
    int e0 = boff[k], e1 = boff[k + 1];
    int m = e1 - e0;
    bool inl = (m <= BCAP);

    cnt[t] = 0; cnt[t + 256] = 0;
    if (inl) for (int i = t; i < m; i += 256) ebuf[i] = binned[e0 + i];
    __syncthreads();
    for (int i = t; i < m; i += 256) {
        uint_t v = inl ? ebuf[i] : binned[e0 + i];
        atomicAdd(&cnt[v >> 17], 1);
    }
    __syncthreads();
    int c0 = cnt[2 * t], c1 = cnt[2 * t + 1];
    int sum = c0 + c1;
    a[t] = sum;
    __syncthreads();
    for (int o = 1; o < 256; o <<= 1) {
        int x = (t >= o) ? a[t - o] : 0;
        __syncthreads();
        a[t] += x;
        __syncthreads();
    }
    int excl = a[t] - sum;
    int base = k * RNG;
    if (2 * t < RNG) { off[base + 2 * t] = e0 + excl; wpos[2 * t] = excl; }
    if (2 * t + 1 < RNG) { off[base + 2 * t + 1] = e0 + excl + c0; wpos[2 * t + 1] = excl + c0; }
    if (k == NBUK - 1 && t == 0) off[NN] = NE;
    __syncthreads();
    for (int i = t; i < m; i += 256) {
        uint_t v = inl ? ebuf[i] : binned[e0 + i];
        int ldst = (int)(v >> 17);
        int r = atomicAdd(&wpos[ldst], 1);
        csr[e0 + r] = (int)(v & 0x1FFFFu);
    }
}

// edge-balanced wave start nodes: wstart[w] = lower_bound(off, w*NE/NWAVES)
__global__ __launch_bounds__(256) void k_wstart(const int* __restrict__ off, int* __restrict__ wstart) {
    int w = blockIdx.x * blockDim.x + threadIdx.x;
    if (w > NWAVES) return;
    if (w == NWAVES) { wstart[w] = NN; return; }
    int t = (int)(((long long)w * NE) / NWAVES);
    int lo = 0, hi = NN;
    while (lo < hi) { int mid = (lo + hi) >> 1; if (off[mid] < t) lo = mid + 1; else hi = mid; }
    wstart[w] = lo;
}

// ---------------- fused layer kernels ----------------
// k_agg: on-the-fly affine(+relu) of bf16 input (folds prev layer's BN2+ReLU),
// GIN aggregation (quad-vectorized gather: 4 neighbors per wave-load), GEMM1,
// BN1 stats, pool of h_L. Lane = (grp = lane>>4 -> neighbor subset, fl = lane&15
// -> feature quad [4fl..4fl+3]); GEMM keeps lane = output feature via LDS buf.

template<int DORELU>
__global__ __launch_bounds__(256) void k_agg(
    const ushort_t* __restrict__ zb,
    const float* __restrict__ stats2p, const float* __restrict__ g2p, const float* __restrict__ b2p,
    const int* __restrict__ csr, const int* __restrict__ off, const int* __restrict__ wstart,
    const float* __restrict__ W1, ushort_t* __restrict__ yb,
    float* __restrict__ stats1,
    const int* __restrict__ gid, float* __restrict__ poolL)
{
    __shared__ __align__(16) float buf[4][64];
    __shared__ int sidx[4][CAP];
    __shared__ float sred[128];
    int lane = threadIdx.x & 63;
    int wslot = threadIdx.x >> 6;
    int wid = blockIdx.x * 4 + wslot;
    int fl = lane & 15;
    int grp = lane >> 4;

    // per-quad affine coefficients (features 4fl..4fl+3)
    float scv0 = 1.f, scv1 = 1.f, scv2 = 1.f, scv3 = 1.f;
    float shv0 = 0.f, shv1 = 0.f, shv2 = 0.f, shv3 = 0.f;
    if (DORELU) {
        int f = 4 * fl;
#define MKCO(q, scq, shq) { \
        float mean = stats2p[f + q] * (1.f / NN); \
        float var  = stats2p[64 + f + q] * (1.f / NN) - mean * mean; \
        scq = rsqrtf(var + BN_EPS) * g2p[f + q]; \
        shq = b2p[f + q] - mean * scq; }
        MKCO(0, scv0, shv0) MKCO(1, scv1, shv1) MKCO(2, scv2, shv2) MKCO(3, scv3, shv3)
#undef MKCO
    }

    float Wc[64];
#pragma unroll
    for (int k = 0; k < 64; k++) Wc[k] = W1[k * 64 + lane];

    float ls = 0.f, lss = 0.f;

    int n0 = wstart[wid], n1 = wstart[wid + 1];

    if (n0 < n1) {
        int e0 = off[n0];
        int eEnd = off[n1];
        int tot = eEnd - e0;
        int lim = min(tot, CAP);
        for (int t = lane; t < lim; t += 64) sidx[wslot][t] = csr[e0 + t];

        int curg = -1;
        float p0 = 0.f, p1 = 0.f, p2 = 0.f, p3 = 0.f;

#define AFF(t, scq, shq) (DORELU ? fmaxf(fmaf(t, scq, shq), 0.f) : (t))
#define UNPK(p, t0, t1, t2, t3) \
        float t0 = AFF(__uint_as_float(p.x << 16), scv0, shv0); \
        float t1 = AFF(__uint_as_float(p.x & 0xFFFF0000u), scv1, shv1); \
        float t2 = AFF(__uint_as_float(p.y << 16), scv2, shv2); \
        float t3 = AFF(__uint_as_float(p.y & 0xFFFF0000u), scv3, shv3);

        for (int n = n0; n < n1; ++n) {
            // self quad (all groups load same addr -> broadcast)
            uint2 sp = *(const uint2*)(zb + ((size_t)n << 6) + (fl << 2));
            UNPK(sp, s0v, s1v, s2v, s3v)

            int g = gid[n];
            if (g != curg) {
                if (curg >= 0 && grp == 0) {
                    atomicAdd(&poolL[curg * 64 + 4 * fl], p0);
                    atomicAdd(&poolL[curg * 64 + 4 * fl + 1], p1);
                    atomicAdd(&poolL[curg * 64 + 4 * fl + 2], p2);
                    atomicAdd(&poolL[curg * 64 + 4 * fl + 3], p3);
                }
                curg = g; p0 = p1 = p2 = p3 = 0.f;
            }
            p0 += s0v; p1 += s1v; p2 += s2v; p3 += s3v;

            float b0 = 0.f, b1 = 0.f, b2 = 0.f, b3 = 0.f;
            int s0l = off[n] - e0, s1l = off[n + 1] - e0;
            int j = s0l + grp;
            if (s1l <= lim) {
                for (; j + 12 < s1l; j += 16) {
                    int i0 = sidx[wslot][j], i1 = sidx[wslot][j + 4],
                        i2 = sidx[wslot][j + 8], i3 = sidx[wslot][j + 12];
                    uint2 q0 = *(const uint2*)(zb + ((size_t)i0 << 6) + (fl << 2));
                    uint2 q1 = *(const uint2*)(zb + ((size_t)i1 << 6) + (fl << 2));
                    uint2 q2 = *(const uint2*)(zb + ((size_t)i2 << 6) + (fl << 2));
                    uint2 q3 = *(const uint2*)(zb + ((size_t)i3 << 6) + (fl << 2));
                    { UNPK(q0, t0, t1, t2, t3) b0 += t0; b1 += t1; b2 += t2; b3 += t3; }
                    { UNPK(q1, t0, t1, t2, t3) b0 += t0; b1 += t1; b2 += t2; b3 += t3; }
                    { UNPK(q2, t0, t1, t2, t3) b0 += t0; b1 += t1; b2 += t2; b3 += t3; }
                    { UNPK(q3, t0, t1, t2, t3) b0 += t0; b1 += t1; b2 += t2; b3 += t3; }
                }
                for (; j < s1l; j += 4) {
                    int i0 = sidx[wslot][j];
                    uint2 q0 = *(const uint2*)(zb + ((size_t)i0 << 6) + (fl << 2));
                    UNPK(q0, t0, t1, t2, t3) b0 += t0; b1 += t1; b2 += t2; b3 += t3;
                }
            } else {
                for (; j < s1l; j += 4) {
                    int i0 = csr[e0 + j];
                    uint2 q0 = *(const uint2*)(zb + ((size_t)i0 << 6) + (fl << 2));
                    UNPK(q0, t0, t1, t2, t3) b0 += t0; b1 += t1; b2 += t2; b3 += t3;
                }
            }
            // combine neighbor subsets across the 4 groups
            b0 += __shfl_xor(b0, 16); b0 += __shfl_xor(b0, 32);
            b1 += __shfl_xor(b1, 16); b1 += __shfl_xor(b1, 32);
            b2 += __shfl_xor(b2, 16); b2 += __shfl_xor(b2, 32);
            b3 += __shfl_xor(b3, 16); b3 += __shfl_xor(b3, 32);

            if (grp == 0) {
                ((float4*)buf[wslot])[fl] = make_float4(s0v + b0, s1v + b1, s2v + b2, s3v + b3);
            }
            // GEMM: lane = output feature
            float yl = 0.f;
#pragma unroll
            for (int k = 0; k < 16; k++) {
                float4 z4 = *(const float4*)&buf[wslot][k * 4];
                yl = fmaf(z4.x, Wc[4 * k], yl);
                yl = fmaf(z4.y, Wc[4 * k + 1], yl);
                yl = fmaf(z4.z, Wc[4 * k + 2], yl);
                yl = fmaf(z4.w, Wc[4 * k + 3], yl);
            }
            yb[(size_t)n * 64 + lane] = f2bf(yl);
            ls += yl;
            lss += yl * yl;
        }
        if (curg >= 0 && grp == 0) {
            atomicAdd(&poolL[curg * 64 + 4 * fl], p0);
            atomicAdd(&poolL[curg * 64 + 4 * fl + 1], p1);
            atomicAdd(&poolL[curg * 64 + 4 * fl + 2], p2);
            atomicAdd(&poolL[curg * 64 + 4 * fl + 3], p3);
        }
#undef AFF
#undef UNPK
    }

    if (threadIdx.x < 128) sred[threadIdx.x] = 0.f;
    __syncthreads();
    atomicAdd(&sred[lane], ls);
    atomicAdd(&sred[64 + lane], lss);
    __syncthreads();
    if (threadIdx.x < 128) atomicAdd(&stats1[threadIdx.x], sred[threadIdx.x]);
}

// k_g2: BN1 apply + ReLU + GEMM2 + BN2 stats; bf16 in/out.

__global__ __launch_bounds__(256) void k_g2(
    const ushort_t* __restrict__ yb, const float* __restrict__ stats1,
    const float* __restrict__ g1, const float* __restrict__ b1,
    const float* __restrict__ W2, ushort_t* __restrict__ zb,
    float* __restrict__ stats2)
{
    __shared__ __align__(16) float buf[4][4][64];
    __shared__ float sred[128];
    int lane = threadIdx.x & 63;
    int wslot = threadIdx.x >> 6;
    int wid = blockIdx.x * 4 + wslot;
    int nw = AGG_BLOCKS * 4;
    int chunk = (NN + nw - 1) / nw;
    int n0 = wid * chunk, n1 = min(NN, n0 + chunk);

    float mean = stats1[lane] * (1.f / NN);
    float var  = stats1[64 + lane] * (1.f / NN) - mean * mean;
    float sc = rsqrtf(var + BN_EPS) * g1[lane];
    float sh = b1[lane] - mean * sc;

    float Wc[64];
#pragma unroll
    for (int k = 0; k < 64; k++) Wc[k] = W2[k * 64 + lane];

    float ls = 0.f, lss = 0.f;
    if (n0 < n1) {
        int n = n0;
        for (; n + 4 <= n1; n += 4) {
            float v0 = fmaxf(fmaf(bf2f(yb[(size_t)n * 64 + lane]), sc, sh), 0.f);
            float v1 = fmaxf(fmaf(bf2f(yb[(size_t)(n + 1) * 64 + lane]), sc, sh), 0.f);
            float v2 = fmaxf(fmaf(bf2f(yb[(size_t)(n + 2) * 64 + lane]), sc, sh), 0.f);
            float v3 = fmaxf(fmaf(bf2f(yb[(size_t)(n + 3) * 64 + lane]), sc, sh), 0.f);
            buf[wslot][0][lane] = v0;
            buf[wslot][1][lane] = v1;
            buf[wslot][2][lane] = v2;
            buf[wslot][3][lane] = v3;
#pragma unroll
            for (int r = 0; r < 4; ++r) {
                float zl = 0.f;
#pragma unroll
                for (int k = 0; k < 16; k++) {
                    float4 t4 = *(const float4*)&buf[wslot][r][k * 4];
                    zl = fmaf(t4.x, Wc[4 * k], zl);
                    zl = fmaf(t4.y, Wc[4 * k + 1], zl);
                    zl = fmaf(t4.z, Wc[4 * k + 2], zl);
                    zl = fmaf(t4.w, Wc[4 * k + 3], zl);
                }
                zb[(size_t)(n + r) * 64 + lane] = f2bf(zl);
                ls += zl;
                lss += zl * zl;
            }
        }
        for (; n < n1; ++n) {
            float v = fmaxf(fmaf(bf2f(yb[(size_t)n * 64 + lane]), sc, sh), 0.f);
            buf[wslot][0][lane] = v;
            float zl = 0.f;
#pragma unroll
            for (int k = 0; k < 16; k++) {
                float4 t4 = *(const float4*)&buf[wslot][0][k * 4];
                zl = fmaf(t4.x, Wc[4 * k], zl);
                zl = fmaf(t4.y, Wc[4 * k + 1], zl);
                zl = fmaf(t4.z, Wc[4 * k + 2], zl);
                zl = fmaf(t4.w, Wc[4 * k + 3], zl);
            }
            zb[(size_t)n * 64 + lane] = f2bf(zl);
            ls += zl;
            lss += zl * zl;
        }
    }

    if (threadIdx.x < 128) sred[threadIdx.x] = 0.f;
    __syncthreads();
    atomicAdd(&sred[lane], ls);
    atomicAdd(&sred[64 + lane], lss);
    __syncthreads();
    if (threadIdx.x < 128) atomicAdd(&stats2[threadIdx.x], sred[threadIdx.x]);
}

// final hidden rep pooling (h_4)

__global__ __launch_bounds__(256) void k_pool4(
    const ushort_t* __restrict__ zb,
    const float* __restrict__ stats2, const float* __restrict__ g2, const float* __restrict__ b2,
    const int* __restrict__ gid, float* __restrict__ pool)
{
    int lane = threadIdx.x & 63;
    int wslot = threadIdx.x >> 6;
    int wid = blockIdx.x * 4 + wslot;
    int nw = gridDim.x * 4;
    int chunk = (NN + nw - 1) / nw;
    int n0 = wid * chunk, n1 = min(NN, n0 + chunk);
    if (n0 >= n1) return;

    float mean = stats2[lane] * (1.f / NN);
    float var  = stats2[64 + lane] * (1.f / NN) - mean * mean;
    float sc = rsqrtf(var + BN_EPS) * g2[lane];
    float sh = b2[lane] - mean * sc;

    int curg = -1;
    float pacc = 0.f;
    for (int n = n0; n < n1; ++n) {
        float v = fmaxf(fmaf(bf2f(zb[(size_t)n * 64 + lane]), sc, sh), 0.f);
        int g = gid[n];
        if (g != curg) {
            if (curg >= 0) atomicAdd(&pool[curg * 64 + lane], pacc);
            curg = g; pacc = 0.f;
        }
        pacc += v;
    }
    if (curg >= 0) atomicAdd(&pool[curg * 64 + lane], pacc);
}

// ---------------- epilogue ----------------

__global__ __launch_bounds__(256) void k_final(
    const float* __restrict__ pooled, const float* __restrict__ pW,
    const float* __restrict__ pb, float* __restrict__ out)
{
    int t = blockIdx.x * blockDim.x + threadIdx.x;
    int g = t >> 4;
    int c = t & 15;
    if (g >= NG) return;
    float acc = 0.f;
#pragma unroll
    for (int i = 0; i < 5; i++) {
        const float* P = pooled + (size_t)i * NG * 64 + g * 64;
        const float* W = pW + i * 64 * 16;
        float a = 0.f;
#pragma unroll
        for (int k = 0; k < 64; k++) a += P[k] * W[k * 16 + c];
        acc += a + pb[i * 16 + c];
    }
    float m = acc;
    for (int o = 1; o < 16; o <<= 1) m = fmaxf(m, __shfl_xor(m, o, 16));
    float e = expf(acc - m);
    float s = e;
    for (int o = 1; o < 16; o <<= 1) s += __shfl_xor(s, o, 16);
    out[g * 16 + c] = acc - m - logf(s);
}

// ---------------- launch ----------------

extern "C" void kernel_launch(void* const* d_in, const int* in_sizes, int n_in,
                              void* d_out, int out_size, void* d_ws, size_t ws_size,
                              hipStream_t stream) {
    const float* feat = (const float*)d_in[0];
    const float* W1   = (const float*)d_in[1];
    const float* W2   = (const float*)d_in[2];
    const float* bn1g = (const float*)d_in[3];
    const float* bn1b = (const float*)d_in[4];
    const float* bn2g = (const float*)d_in[5];
    const float* bn2b = (const float*)d_in[6];
    const float* pW   = (const float*)d_in[7];
    const float* pb   = (const float*)d_in[8];
    const int* src = (const int*)d_in[9];
    const int* dst = (const int*)d_in[10];
    const int* gid = (const int*)d_in[11];
    float* out = (float*)d_out;

    char* ws = (char*)d_ws;
    size_t o = 0;
    auto alloc = [&](size_t bytes) {
        void* p = ws + o;
        o += (bytes + 255) & ~(size_t)255;
        return p;
    };
    ushort_t* zb  = (ushort_t*)alloc((size_t)NN * 64 * 2);
    ushort_t* yb  = (ushort_t*)alloc((size_t)NN * 64 * 2);
    float* pooled = (float*)alloc((size_t)5 * NG * 64 * 4);
    float* stats  = (float*)alloc(1024 * 4);
    int* off  = (int*)alloc((size_t)(NN + 1) * 4);
    int* csr  = (int*)alloc((size_t)NE * 4);
    uint_t* binned = (uint_t*)alloc((size_t)NE * 4);
    int* cmat = (int*)alloc((size_t)BB * NBUK * 4);
    int* wmat = (int*)alloc((size_t)BB * NBUK * 4);
    int* bcnt = (int*)alloc(NBUK * 4);
    int* boff = (int*)alloc((NBUK + 1) * 4);
    int* wstart = (int*)alloc((NWAVES + 1) * 4);

    k_init<<<256, 256, 0, stream>>>(pooled, stats, bcnt);
    k_f2bf<<<1024, 256, 0, stream>>>((const float4*)feat, (uint2*)zb);
    k_cnt<<<BB, 256, 0, stream>>>(dst, cmat, bcnt);
    k_bucket_scan<<<1, 256, 0, stream>>>(bcnt, boff);
    k_boffscan<<<NBUK, 256, 0, stream>>>(cmat, boff, wmat);
    k_bin2<<<BB, 256, 0, stream>>>(src, dst, wmat, binned);
    k_bucket_finish<<<NBUK, 256, 0, stream>>>(binned, boff, off, csr);
    k_wstart<<<(NWAVES + 1 + 255) / 256, 256, 0, stream>>>(off, wstart);

    for (int L = 0; L < 4; ++L) {
        float* s1 = stats + L * 256;
        float* s2 = s1 + 128;
        if (L == 0) {
            k_agg<0><<<AGG_BLOCKS, 256, 0, stream>>>(zb, nullptr, nullptr, nullptr,
                                                     csr, off, wstart, W1 + L * 4096, yb, s1,
                                                     gid, pooled + (size_t)L * NG * 64);
        } else {
            k_agg<1><<<AGG_BLOCKS, 256, 0, stream>>>(zb, stats + (L - 1) * 256 + 128,
                                                     bn2g + (L - 1) * 64, bn2b + (L - 1) * 64,
                                                     csr, off, wstart, W1 + L * 4096, yb, s1,
                                                     gid, pooled + (size_t)L * NG * 64);
        }
        k_g2<<<AGG_BLOCKS, 256, 0, stream>>>(yb, s1, bn1g + L * 64, bn1b + L * 64,
                                             W2 + L * 4096, zb, s2);
    }
    k_pool4<<<AGG_BLOCKS, 256, 0, stream>>>(zb, stats + 3 * 256 + 128, bn2g + 3 * 64, bn2b + 3 * 64,
                                            gid, pooled + (size_t)4 * NG * 64);
    k_final<<<(NG * 16 + 255) / 256, 256, 0, stream>>>(pooled, pW, pb, out);
}